// Round 4
// baseline (138.084 us; speedup 1.0000x reference)
//
#include <hip/hip_runtime.h>
#include <hip/hip_bf16.h>

using bf16x8 = __attribute__((ext_vector_type(8))) __bf16;
using f32x4  = __attribute__((ext_vector_type(4))) float;

#define MTOT   16384
#define DMODEL 1024
#define DSTATE 64
#define KBIG   1088

__device__ __forceinline__ ushort f2b(float f) {
  __hip_bfloat16 h = __float2bfloat16(f);
  return *reinterpret_cast<ushort*>(&h);
}

// async global->LDS, 16 bytes per lane. LDS dest = wave-uniform base + lane*16.
__device__ __forceinline__ void gld_lds16(const ushort* g, const char* l) {
  using gptr_t = const __attribute__((address_space(1))) uint32_t*;
  using lptr_t = __attribute__((address_space(3))) uint32_t*;
  __builtin_amdgcn_global_load_lds(
      reinterpret_cast<gptr_t>(reinterpret_cast<uintptr_t>(g)),
      reinterpret_cast<lptr_t>(static_cast<uint32_t>(reinterpret_cast<uintptr_t>(l))),
      16, 0, 0);
}

#define BARRIER() do { asm volatile("" ::: "memory"); __builtin_amdgcn_s_barrier(); asm volatile("" ::: "memory"); } while (0)
#define VMCNT4() asm volatile("s_waitcnt vmcnt(4)" ::: "memory")
#define VMCNT0() asm volatile("s_waitcnt vmcnt(0)" ::: "memory")

// ---------------- prep params ----------------
// Wt[n][k] = bf16( k<64 ? C[k][n] : D[k-64][n] ); Btu[s][k] = bf16(B[k][s]); aSig = sigmoid(A)
__global__ void prep_params(const float* __restrict__ A_diag, const float* __restrict__ B,
                            const float* __restrict__ C, const float* __restrict__ D,
                            ushort* __restrict__ Wt, ushort* __restrict__ Btu,
                            float* __restrict__ aSig) {
  int i = blockIdx.x * blockDim.x + threadIdx.x;
  int stride = gridDim.x * blockDim.x;
  for (int idx = i; idx < DMODEL * KBIG; idx += stride) {
    int n = idx / KBIG, k = idx % KBIG;
    float v = (k < DSTATE) ? C[k * DMODEL + n] : D[(size_t)(k - DSTATE) * DMODEL + n];
    Wt[idx] = f2b(v);
  }
  for (int idx = i; idx < DSTATE * DMODEL; idx += stride) {
    int s = idx >> 10, k = idx & 1023;
    Btu[idx] = f2b(B[k * DSTATE + s]);
  }
  if (i < DSTATE) aSig[i] = 1.0f / (1.0f + expf(-A_diag[i]));
}

// ---------------- fused: x -> Z(bf16), u = x@B -> chunk-local scan -> Uloc, carry ---------
// Block = 64 rows (one per block of M), 4 waves. K=1024 in 8 chunks of 128.
// Wave w owns rows w*16..w*16+15 = one scan chunk (TC=16). Chunk id g = bid*4+w.
__global__ __launch_bounds__(256) void fused_xu(const float* __restrict__ x,
    const ushort* __restrict__ Btu, const float* __restrict__ aSig,
    ushort* __restrict__ Z, float* __restrict__ Uloc, float* __restrict__ carry) {
  __shared__ ushort As[64][136];   // +8 pad: frag reads 2-way only
  __shared__ float  Ul[64][68];    // +4 pad
  int tid = threadIdx.x;
  int w = tid >> 6, lane = tid & 63;
  int l16 = lane & 15, lh = lane >> 4;
  int row0 = blockIdx.x * 64;

  f32x4 acc[4] = {};
  float4 xv[8];
#pragma unroll
  for (int p = 0; p < 8; ++p) {
    int fi = p * 256 + tid;
    int r = fi >> 5, kq = fi & 31;
    xv[p] = *reinterpret_cast<const float4*>(x + (size_t)(row0 + r) * 1024 + kq * 4);
  }
  for (int c = 0; c < 8; ++c) {
    int k0 = c * 128;
#pragma unroll
    for (int p = 0; p < 8; ++p) {
      int fi = p * 256 + tid;
      int r = fi >> 5, kq = fi & 31;
      ushort4 o;
      o.x = f2b(xv[p].x); o.y = f2b(xv[p].y); o.z = f2b(xv[p].z); o.w = f2b(xv[p].w);
      *reinterpret_cast<ushort4*>(&Z[(size_t)(row0 + r) * KBIG + DSTATE + k0 + kq * 4]) = o;
      *reinterpret_cast<ushort4*>(&As[r][kq * 4]) = o;
    }
    __syncthreads();
    if (c < 7) {
      int k1 = k0 + 128;
#pragma unroll
      for (int p = 0; p < 8; ++p) {
        int fi = p * 256 + tid;
        int r = fi >> 5, kq = fi & 31;
        xv[p] = *reinterpret_cast<const float4*>(x + (size_t)(row0 + r) * 1024 + k1 + kq * 4);
      }
    }
#pragma unroll
    for (int ks = 0; ks < 4; ++ks) {
      bf16x8 af = *reinterpret_cast<const bf16x8*>(&As[w * 16 + l16][ks * 32 + lh * 8]);
#pragma unroll
      for (int n = 0; n < 4; ++n) {
        bf16x8 bf = *reinterpret_cast<const bf16x8*>(
            &Btu[(size_t)(n * 16 + l16) * 1024 + k0 + ks * 32 + lh * 8]);
        acc[n] = __builtin_amdgcn_mfma_f32_16x16x32_bf16(af, bf, acc[n], 0, 0, 0);
      }
    }
    __syncthreads();
  }
  // acc -> LDS (u values), then per-wave sequential scan over 16 rows
#pragma unroll
  for (int n = 0; n < 4; ++n)
#pragma unroll
    for (int j = 0; j < 4; ++j)
      Ul[w * 16 + lh * 4 + j][n * 16 + l16] = acc[n][j];
  __syncthreads();
  int s = lane;
  float as = aSig[s];
  float h = 0.0f;
  int g = blockIdx.x * 4 + w;
#pragma unroll
  for (int i = 0; i < 16; ++i) {
    h = fmaf(as, h, Ul[w * 16 + i][s]);
    Uloc[(size_t)(g * 16 + i) * 64 + s] = h;
  }
  carry[(size_t)g * 64 + s] = h;
}

// ---------------- scan fix: combine carries, write bf16 h into Z[:,0:64] -------------
__global__ __launch_bounds__(256) void scan_fix2(const float* __restrict__ aSig,
    const float* __restrict__ Uloc, const float* __restrict__ carry,
    ushort* __restrict__ Z) {
  int w = threadIdx.x >> 6, s = threadIdx.x & 63;
  int g = blockIdx.x * 4 + w;          // 0..1023
  int b = g >> 8, c = g & 255;
  float as = aSig[s];
  float aL = as;
#pragma unroll
  for (int q = 0; q < 4; ++q) aL *= aL;  // as^16
  float H = 0.0f;
  const float* cb = carry + ((size_t)b << 8) * 64 + s;
  for (int j = 0; j < c; ++j) H = fmaf(aL, H, cb[(size_t)j * 64]);
  float p = as;
  size_t ubase = (size_t)g * 16 * 64 + s;
  size_t zbase = (size_t)(g * 16) * KBIG + s;
#pragma unroll
  for (int i = 0; i < 16; ++i) {
    float h = fmaf(p, H, Uloc[ubase + (size_t)i * 64]);
    p *= as;
    Z[zbase + (size_t)i * KBIG] = f2b(h);
  }
}

// ---------------- 256x256 8-phase GEMM: y = Z @ Wt^T ----------------
// 512 thr = 8 waves (2 x 4). LDS: 2 bufs x (A[256][64] + B[256][64]) = 128 KiB.
// 3-bit XOR swizzle (byte ^= (row&7)<<4), applied on the global SOURCE address
// (linear gld_lds dest) and on the ds_read address — both-sides (rule #21).
__global__ __launch_bounds__(512) void gemm256(const ushort* __restrict__ A, int lda,
                                               const ushort* __restrict__ Bt, int ldb,
                                               float* __restrict__ Cc, int ldc, int K) {
  extern __shared__ __align__(128) char smem[];
  const int tid = threadIdx.x;
  const int wid = tid >> 6, lane = tid & 63;
  const int wm = wid >> 2, wn = wid & 3;      // 2 x 4 wave grid
  const int l16 = lane & 15, lh = lane >> 4;

  int bid = blockIdx.x;
  int swz = (bid & 7) * ((int)gridDim.x >> 3) + (bid >> 3);  // XCD swizzle (nwg%8==0)
  const int bmRow = (swz >> 2) * 256;
  const int bnCol = (swz & 3) * 256;

  const int NT = K / 64;

  // read-side swizzle: byte col = (ks*64 | lh*16) ^ ((l16&7)*16) = (cswz ^ ks*64)
  const int cswz = ((lh ^ (l16 & 7)) << 4);
  // stage-side: source col (ushorts) pre-XORed so linear LDS dest lands swizzled
  const int sRow = lane >> 3;
  const int sCol = (((lane & 7) ^ (lane >> 3)) << 3);

  f32x4 acc[8][4] = {};
  bf16x8 aR[8], bR[8];

  auto stageA = [&](int buf, int t, int h) {
    size_t r = (size_t)(bmRow + h * 128 + wid * 8 + sRow);
    const ushort* g0 = A + r * (size_t)lda + t * 64 + sCol;
    const char* d = smem + buf * 65536 + (h * 128 + wid * 8) * 128;
    gld_lds16(g0, d);
    gld_lds16(g0 + (size_t)64 * lda, d + 64 * 128);
  };
  auto stageB = [&](int buf, int t, int h) {
    size_t r = (size_t)(bnCol + h * 128 + wid * 8 + sRow);
    const ushort* g0 = Bt + r * (size_t)ldb + t * 64 + sCol;
    const char* d = smem + buf * 65536 + 32768 + (h * 128 + wid * 8) * 128;
    gld_lds16(g0, d);
    gld_lds16(g0 + (size_t)64 * ldb, d + 64 * 128);
  };
  auto loadA = [&](int buf, int qm) {
#pragma unroll
    for (int m = 0; m < 4; ++m)
#pragma unroll
      for (int ks = 0; ks < 2; ++ks)
        aR[m * 2 + ks] = *reinterpret_cast<const bf16x8*>(
            smem + buf * 65536 + (wm * 128 + qm * 64 + m * 16 + l16) * 128 + (cswz ^ (ks * 64)));
  };
  auto loadB = [&](int buf, int qn) {
#pragma unroll
    for (int n = 0; n < 2; ++n)
#pragma unroll
      for (int ks = 0; ks < 2; ++ks)
        bR[qn * 4 + n * 2 + ks] = *reinterpret_cast<const bf16x8*>(
            smem + buf * 65536 + 32768 + (wn * 64 + qn * 32 + n * 16 + l16) * 128 + (cswz ^ (ks * 64)));
  };
  auto mfmaQ = [&](int qm, int qn) {
    __builtin_amdgcn_s_setprio(1);
    __builtin_amdgcn_sched_barrier(0);
#pragma unroll
    for (int ks = 0; ks < 2; ++ks)      // ks OUTER: dependent acc hits 8 instrs apart
#pragma unroll
      for (int m = 0; m < 4; ++m)
#pragma unroll
        for (int n = 0; n < 2; ++n)
          acc[qm * 4 + m][qn * 2 + n] = __builtin_amdgcn_mfma_f32_16x16x32_bf16(
              aR[m * 2 + ks], bR[qn * 4 + n * 2 + ks], acc[qm * 4 + m][qn * 2 + n], 0, 0, 0);
    __builtin_amdgcn_sched_barrier(0);
    __builtin_amdgcn_s_setprio(0);
  };

  // prologue: stage tiles 0 (buf0) and 1 (buf1), drain, barrier
  stageA(0, 0, 0); stageA(0, 0, 1); stageB(0, 0, 0); stageB(0, 0, 1);
  if (1 < NT) { stageA(1, 1, 0); stageA(1, 1, 1); stageB(1, 1, 0); stageB(1, 1, 1); }
  VMCNT0();
  BARRIER();

  for (int t = 0; t < NT; t += 2) {
    const bool s01 = (t > 0) && (t + 1 < NT);
    const bool s23 = (t + 2 < NT);
    const bool s67 = (t + 3 < NT);
    // ---- tile t @ buf0 ----
    loadA(0, 0); loadB(0, 0);
    if (s01) stageA(1, t + 1, 0);
    BARRIER(); mfmaQ(0, 0); BARRIER();
    loadB(0, 1);
    if (s01) stageA(1, t + 1, 1);
    BARRIER(); mfmaQ(0, 1); BARRIER();
    loadA(0, 1);
    if (s23) stageB(0, t + 2, 0);
    BARRIER(); mfmaQ(1, 0); BARRIER();
    if (s23) stageB(0, t + 2, 1);
    BARRIER(); mfmaQ(1, 1);
    if (s23) { VMCNT4(); } else { VMCNT0(); }
    BARRIER();
    // ---- tile t+1 @ buf1 ----
    if (t + 1 < NT) {
      loadA(1, 0); loadB(1, 0);
      if (s23) stageA(0, t + 2, 0);
      BARRIER(); mfmaQ(0, 0); BARRIER();
      loadB(1, 1);
      if (s23) stageA(0, t + 2, 1);
      BARRIER(); mfmaQ(0, 1); BARRIER();
      loadA(1, 1);
      if (s67) stageB(1, t + 3, 0);
      BARRIER(); mfmaQ(1, 0); BARRIER();
      if (s67) stageB(1, t + 3, 1);
      BARRIER(); mfmaQ(1, 1);
      if (s67) { VMCNT4(); } else { VMCNT0(); }
      BARRIER();
    }
  }

  // epilogue
#pragma unroll
  for (int i = 0; i < 8; ++i)
#pragma unroll
    for (int jn = 0; jn < 4; ++jn)
#pragma unroll
      for (int j = 0; j < 4; ++j) {
        int r = bmRow + wm * 128 + (i >> 2) * 64 + (i & 3) * 16 + lh * 4 + j;
        int c = bnCol + wn * 64 + (jn >> 1) * 32 + (jn & 1) * 16 + l16;
        Cc[(size_t)r * ldc + c] = acc[i][jn][j];
      }
}

extern "C" void kernel_launch(void* const* d_in, const int* in_sizes, int n_in,
                              void* d_out, int out_size, void* d_ws, size_t ws_size,
                              hipStream_t stream) {
  const float* x      = (const float*)d_in[0];
  const float* A_diag = (const float*)d_in[1];
  const float* B      = (const float*)d_in[2];
  const float* C      = (const float*)d_in[3];
  const float* D      = (const float*)d_in[4];
  float* y = (float*)d_out;

  char* w = (char*)d_ws;
  ushort* Z     = (ushort*)(w);                 // [16384][1088] bf16  35,651,584
  ushort* Wt    = (ushort*)(w + 35651584);      // [1024][1088] bf16    2,228,224
  ushort* Btu   = (ushort*)(w + 37879808);      // [64][1024] bf16        131,072
  float*  Uloc  = (float*) (w + 38010880);      // [16384][64] f32      4,194,304
  float*  carry = (float*) (w + 42205184);      // [1024][64] f32         262,144
  float*  aSig  = (float*) (w + 42467328);      // [64] f32

  static bool attr_set = false;
  if (!attr_set) {
    (void)hipFuncSetAttribute(reinterpret_cast<const void*>(&gemm256),
                              hipFuncAttributeMaxDynamicSharedMemorySize, 131072);
    attr_set = true;
  }

  prep_params<<<dim3(1024), dim3(256), 0, stream>>>(A_diag, B, C, D, Wt, Btu, aSig);
  fused_xu<<<dim3(256), dim3(256), 0, stream>>>(x, Btu, aSig, Z, Uloc, carry);
  scan_fix2<<<dim3(256), dim3(256), 0, stream>>>(aSig, Uloc, carry, Z);
  // y = [h|x] @ [C;D] : M=16384, N=1024, K=1088  (256x256 tiles -> 256 blocks)
  gemm256<<<dim3(64 * 4), dim3(512), 131072, stream>>>(Z, KBIG, Wt, KBIG, y, DMODEL, KBIG);
}

// Round 5
// 89.111 us; speedup vs baseline: 1.5496x; 1.5496x over previous
//
#include <hip/hip_runtime.h>
#include <hip/hip_bf16.h>

using bf16x8 = __attribute__((ext_vector_type(8))) __bf16;
using f32x4  = __attribute__((ext_vector_type(4))) float;

#define MTOT   16384
#define DMODEL 1024
#define DSTATE 64
#define KBIG   1088

__device__ __forceinline__ ushort f2b(float f) {
  __hip_bfloat16 h = __float2bfloat16(f);
  return *reinterpret_cast<ushort*>(&h);
}

// async global->LDS, 16 bytes per lane. LDS dest = wave-uniform base + lane*16.
__device__ __forceinline__ void gld_lds16(const ushort* g, const char* l) {
  using gptr_t = const __attribute__((address_space(1))) uint32_t*;
  using lptr_t = __attribute__((address_space(3))) uint32_t*;
  __builtin_amdgcn_global_load_lds(
      reinterpret_cast<gptr_t>(reinterpret_cast<uintptr_t>(g)),
      reinterpret_cast<lptr_t>(static_cast<uint32_t>(reinterpret_cast<uintptr_t>(l))),
      16, 0, 0);
}

#define BARRIER() do { asm volatile("" ::: "memory"); __builtin_amdgcn_s_barrier(); asm volatile("" ::: "memory"); } while (0)
#define VMCNT4() asm volatile("s_waitcnt vmcnt(4)" ::: "memory")
#define VMCNT0() asm volatile("s_waitcnt vmcnt(0)" ::: "memory")

// ---------------- prep params ----------------
__global__ void prep_params(const float* __restrict__ A_diag, const float* __restrict__ B,
                            const float* __restrict__ C, const float* __restrict__ D,
                            ushort* __restrict__ Wt, ushort* __restrict__ Btu,
                            float* __restrict__ aSig) {
  int i = blockIdx.x * blockDim.x + threadIdx.x;
  int stride = gridDim.x * blockDim.x;
  for (int idx = i; idx < DMODEL * KBIG; idx += stride) {
    int n = idx / KBIG, k = idx % KBIG;
    float v = (k < DSTATE) ? C[k * DMODEL + n] : D[(size_t)(k - DSTATE) * DMODEL + n];
    Wt[idx] = f2b(v);
  }
  for (int idx = i; idx < DSTATE * DMODEL; idx += stride) {
    int s = idx >> 10, k = idx & 1023;
    Btu[idx] = f2b(B[k * DSTATE + s]);
  }
  if (i < DSTATE) aSig[i] = 1.0f / (1.0f + expf(-A_diag[i]));
}

// ---------------- fused: x -> Z(bf16), u = x@B -> chunk-local scan -> Uloc, carry ---------
// Block = 64 rows, 4 waves. Wave w owns rows w*16..w*16+15 = one scan chunk (TC=16).
__global__ __launch_bounds__(256) void fused_xu(const float* __restrict__ x,
    const ushort* __restrict__ Btu, const float* __restrict__ aSig,
    ushort* __restrict__ Z, float* __restrict__ Uloc, float* __restrict__ carry) {
  __shared__ ushort As[64][136];
  __shared__ float  Ul[64][68];
  int tid = threadIdx.x;
  int w = tid >> 6, lane = tid & 63;
  int l16 = lane & 15, lh = lane >> 4;
  int row0 = blockIdx.x * 64;

  f32x4 acc[4] = {};
  float4 xv[8];
#pragma unroll
  for (int p = 0; p < 8; ++p) {
    int fi = p * 256 + tid;
    int r = fi >> 5, kq = fi & 31;
    xv[p] = *reinterpret_cast<const float4*>(x + (size_t)(row0 + r) * 1024 + kq * 4);
  }
  for (int c = 0; c < 8; ++c) {
    int k0 = c * 128;
#pragma unroll
    for (int p = 0; p < 8; ++p) {
      int fi = p * 256 + tid;
      int r = fi >> 5, kq = fi & 31;
      ushort4 o;
      o.x = f2b(xv[p].x); o.y = f2b(xv[p].y); o.z = f2b(xv[p].z); o.w = f2b(xv[p].w);
      *reinterpret_cast<ushort4*>(&Z[(size_t)(row0 + r) * KBIG + DSTATE + k0 + kq * 4]) = o;
      *reinterpret_cast<ushort4*>(&As[r][kq * 4]) = o;
    }
    __syncthreads();
    if (c < 7) {
      int k1 = k0 + 128;
#pragma unroll
      for (int p = 0; p < 8; ++p) {
        int fi = p * 256 + tid;
        int r = fi >> 5, kq = fi & 31;
        xv[p] = *reinterpret_cast<const float4*>(x + (size_t)(row0 + r) * 1024 + k1 + kq * 4);
      }
    }
#pragma unroll
    for (int ks = 0; ks < 4; ++ks) {
      bf16x8 af = *reinterpret_cast<const bf16x8*>(&As[w * 16 + l16][ks * 32 + lh * 8]);
#pragma unroll
      for (int n = 0; n < 4; ++n) {
        bf16x8 bf = *reinterpret_cast<const bf16x8*>(
            &Btu[(size_t)(n * 16 + l16) * 1024 + k0 + ks * 32 + lh * 8]);
        acc[n] = __builtin_amdgcn_mfma_f32_16x16x32_bf16(af, bf, acc[n], 0, 0, 0);
      }
    }
    __syncthreads();
  }
#pragma unroll
  for (int n = 0; n < 4; ++n)
#pragma unroll
    for (int j = 0; j < 4; ++j)
      Ul[w * 16 + lh * 4 + j][n * 16 + l16] = acc[n][j];
  __syncthreads();
  int s = lane;
  float as = aSig[s];
  float h = 0.0f;
  int g = blockIdx.x * 4 + w;
#pragma unroll
  for (int i = 0; i < 16; ++i) {
    h = fmaf(as, h, Ul[w * 16 + i][s]);
    Uloc[(size_t)(g * 16 + i) * 64 + s] = h;
  }
  carry[(size_t)g * 64 + s] = h;
}

// ---------------- hierarchical carry scan: chunk carries -> exclusive prefixes -----
// 1 block, 4 waves. Wave b = batch (4096 rows = 256 chunks), lane = state s.
// Loads batched 16-wide (independent addrs) so the serial chain is FMA-only.
__global__ __launch_bounds__(256) void carry_scan(const float* __restrict__ aSig,
    const float* __restrict__ carry, float* __restrict__ Hpref) {
  int b = threadIdx.x >> 6, s = threadIdx.x & 63;
  float as = aSig[s];
  float aL = as;
#pragma unroll
  for (int q = 0; q < 4; ++q) aL *= aL;  // as^16
  const float* cb = carry + ((size_t)b * 256) * 64 + s;
  float* hp = Hpref + ((size_t)b * 256) * 64 + s;
  float H = 0.0f;
  for (int c0 = 0; c0 < 256; c0 += 16) {
    float v[16];
#pragma unroll
    for (int i = 0; i < 16; ++i) v[i] = cb[(size_t)(c0 + i) * 64];
#pragma unroll
    for (int i = 0; i < 16; ++i) {
      hp[(size_t)(c0 + i) * 64] = H;
      H = fmaf(aL, H, v[i]);
    }
  }
}

// ---------------- scan fix: apply prefix, write bf16 h into Z[:,0:64] -------------
__global__ __launch_bounds__(256) void scan_fix2(const float* __restrict__ aSig,
    const float* __restrict__ Uloc, const float* __restrict__ Hpref,
    ushort* __restrict__ Z) {
  int w = threadIdx.x >> 6, s = threadIdx.x & 63;
  int g = blockIdx.x * 4 + w;          // 0..1023
  float as = aSig[s];
  float H = Hpref[(size_t)g * 64 + s];
  float p = as;
  size_t ubase = (size_t)g * 16 * 64 + s;
  size_t zbase = (size_t)(g * 16) * KBIG + s;
#pragma unroll
  for (int i = 0; i < 16; ++i) {
    float h = fmaf(p, H, Uloc[ubase + (size_t)i * 64]);
    p *= as;
    Z[zbase + (size_t)i * KBIG] = f2b(h);
  }
}

// ---------------- 256x256 8-phase GEMM: y = Z @ Wt^T ----------------
__global__ __launch_bounds__(512) void gemm256(const ushort* __restrict__ A, int lda,
                                               const ushort* __restrict__ Bt, int ldb,
                                               float* __restrict__ Cc, int ldc, int K) {
  extern __shared__ __align__(128) char smem[];
  const int tid = threadIdx.x;
  const int wid = tid >> 6, lane = tid & 63;
  const int wm = wid >> 2, wn = wid & 3;
  const int l16 = lane & 15, lh = lane >> 4;

  int bid = blockIdx.x;
  int swz = (bid & 7) * ((int)gridDim.x >> 3) + (bid >> 3);
  const int bmRow = (swz >> 2) * 256;
  const int bnCol = (swz & 3) * 256;

  const int NT = K / 64;

  const int cswz = ((lh ^ (l16 & 7)) << 4);
  const int sRow = lane >> 3;
  const int sCol = (((lane & 7) ^ (lane >> 3)) << 3);

  f32x4 acc[8][4] = {};
  bf16x8 aR[8], bR[8];

  auto stageA = [&](int buf, int t, int h) {
    size_t r = (size_t)(bmRow + h * 128 + wid * 8 + sRow);
    const ushort* g0 = A + r * (size_t)lda + t * 64 + sCol;
    const char* d = smem + buf * 65536 + (h * 128 + wid * 8) * 128;
    gld_lds16(g0, d);
    gld_lds16(g0 + (size_t)64 * lda, d + 64 * 128);
  };
  auto stageB = [&](int buf, int t, int h) {
    size_t r = (size_t)(bnCol + h * 128 + wid * 8 + sRow);
    const ushort* g0 = Bt + r * (size_t)ldb + t * 64 + sCol;
    const char* d = smem + buf * 65536 + 32768 + (h * 128 + wid * 8) * 128;
    gld_lds16(g0, d);
    gld_lds16(g0 + (size_t)64 * ldb, d + 64 * 128);
  };
  auto loadA = [&](int buf, int qm) {
#pragma unroll
    for (int m = 0; m < 4; ++m)
#pragma unroll
      for (int ks = 0; ks < 2; ++ks)
        aR[m * 2 + ks] = *reinterpret_cast<const bf16x8*>(
            smem + buf * 65536 + (wm * 128 + qm * 64 + m * 16 + l16) * 128 + (cswz ^ (ks * 64)));
  };
  auto loadB = [&](int buf, int qn) {
#pragma unroll
    for (int n = 0; n < 2; ++n)
#pragma unroll
      for (int ks = 0; ks < 2; ++ks)
        bR[qn * 4 + n * 2 + ks] = *reinterpret_cast<const bf16x8*>(
            smem + buf * 65536 + 32768 + (wn * 64 + qn * 32 + n * 16 + l16) * 128 + (cswz ^ (ks * 64)));
  };
  auto mfmaQ = [&](int qm, int qn) {
    __builtin_amdgcn_s_setprio(1);
    __builtin_amdgcn_sched_barrier(0);
#pragma unroll
    for (int ks = 0; ks < 2; ++ks)
#pragma unroll
      for (int m = 0; m < 4; ++m)
#pragma unroll
        for (int n = 0; n < 2; ++n)
          acc[qm * 4 + m][qn * 2 + n] = __builtin_amdgcn_mfma_f32_16x16x32_bf16(
              aR[m * 2 + ks], bR[qn * 4 + n * 2 + ks], acc[qm * 4 + m][qn * 2 + n], 0, 0, 0);
    __builtin_amdgcn_sched_barrier(0);
    __builtin_amdgcn_s_setprio(0);
  };

  stageA(0, 0, 0); stageA(0, 0, 1); stageB(0, 0, 0); stageB(0, 0, 1);
  if (1 < NT) { stageA(1, 1, 0); stageA(1, 1, 1); stageB(1, 1, 0); stageB(1, 1, 1); }
  VMCNT0();
  BARRIER();

  for (int t = 0; t < NT; t += 2) {
    const bool s01 = (t > 0) && (t + 1 < NT);
    const bool s23 = (t + 2 < NT);
    const bool s67 = (t + 3 < NT);
    loadA(0, 0); loadB(0, 0);
    if (s01) stageA(1, t + 1, 0);
    BARRIER(); mfmaQ(0, 0); BARRIER();
    loadB(0, 1);
    if (s01) stageA(1, t + 1, 1);
    BARRIER(); mfmaQ(0, 1); BARRIER();
    loadA(0, 1);
    if (s23) stageB(0, t + 2, 0);
    BARRIER(); mfmaQ(1, 0); BARRIER();
    if (s23) stageB(0, t + 2, 1);
    BARRIER(); mfmaQ(1, 1);
    if (s23) { VMCNT4(); } else { VMCNT0(); }
    BARRIER();
    if (t + 1 < NT) {
      loadA(1, 0); loadB(1, 0);
      if (s23) stageA(0, t + 2, 0);
      BARRIER(); mfmaQ(0, 0); BARRIER();
      loadB(1, 1);
      if (s23) stageA(0, t + 2, 1);
      BARRIER(); mfmaQ(0, 1); BARRIER();
      loadA(1, 1);
      if (s67) stageB(1, t + 3, 0);
      BARRIER(); mfmaQ(1, 0); BARRIER();
      if (s67) stageB(1, t + 3, 1);
      BARRIER(); mfmaQ(1, 1);
      if (s67) { VMCNT4(); } else { VMCNT0(); }
      BARRIER();
    }
  }

#pragma unroll
  for (int i = 0; i < 8; ++i)
#pragma unroll
    for (int jn = 0; jn < 4; ++jn)
#pragma unroll
      for (int j = 0; j < 4; ++j) {
        int r = bmRow + wm * 128 + (i >> 2) * 64 + (i & 3) * 16 + lh * 4 + j;
        int c = bnCol + wn * 64 + (jn >> 1) * 32 + (jn & 1) * 16 + l16;
        Cc[(size_t)r * ldc + c] = acc[i][jn][j];
      }
}

extern "C" void kernel_launch(void* const* d_in, const int* in_sizes, int n_in,
                              void* d_out, int out_size, void* d_ws, size_t ws_size,
                              hipStream_t stream) {
  const float* x      = (const float*)d_in[0];
  const float* A_diag = (const float*)d_in[1];
  const float* B      = (const float*)d_in[2];
  const float* C      = (const float*)d_in[3];
  const float* D      = (const float*)d_in[4];
  float* y = (float*)d_out;

  char* w = (char*)d_ws;
  ushort* Z     = (ushort*)(w);                 // [16384][1088] bf16  35,651,584
  ushort* Wt    = (ushort*)(w + 35651584);      // [1024][1088] bf16    2,228,224
  ushort* Btu   = (ushort*)(w + 37879808);      // [64][1024] bf16        131,072
  float*  Uloc  = (float*) (w + 38010880);      // [16384][64] f32      4,194,304
  float*  carry = (float*) (w + 42205184);      // [1024][64] f32         262,144
  float*  Hpref = (float*) (w + 42467328);      // [1024][64] f32         262,144
  float*  aSig  = (float*) (w + 42729472);      // [64] f32

  (void)hipFuncSetAttribute(reinterpret_cast<const void*>(&gemm256),
                            hipFuncAttributeMaxDynamicSharedMemorySize, 131072);

  prep_params<<<dim3(1024), dim3(256), 0, stream>>>(A_diag, B, C, D, Wt, Btu, aSig);
  fused_xu<<<dim3(256), dim3(256), 0, stream>>>(x, Btu, aSig, Z, Uloc, carry);
  carry_scan<<<dim3(1), dim3(256), 0, stream>>>(aSig, carry, Hpref);
  scan_fix2<<<dim3(256), dim3(256), 0, stream>>>(aSig, Uloc, Hpref, Z);
  // y = [h|x] @ [C;D] : M=16384, N=1024, K=1088  (256x256 tiles -> 256 blocks)
  gemm256<<<dim3(64 * 4), dim3(512), 131072, stream>>>(Z, KBIG, Wt, KBIG, y, DMODEL, KBIG);
}